// Round 6
// baseline (380.634 us; speedup 1.0000x reference)
//
#include <hip/hip_runtime.h>
#include <math.h>

#define DDIM 2048
#define KP 8
#define BLOCK 256
#define WPB (BLOCK / 64)

typedef float f4 __attribute__((ext_vector_type(4)));

__device__ __forceinline__ unsigned short f32_to_bf16_rne(float f) {
    unsigned u = __float_as_uint(f);
    unsigned r = u + 0x7FFFu + ((u >> 16) & 1u);
    return (unsigned short)(r >> 16);
}

__device__ __forceinline__ float gelu_f(float x) {
    // 0.5*x*(1+tanh(y)) == x * sigmoid(2y),  y = 0.79788456*(x+0.044715x^3)
    float x2 = x * x;
    float inner = x * fmaf(0.044715f, x2, 1.0f);
    float e = __expf(-1.5957691216057308f * inner);   // exp(-2y)
    return x * __builtin_amdgcn_rcpf(1.0f + e);
}

__device__ __forceinline__ float wave_reduce_add(float v) {
#pragma unroll
    for (int m = 32; m >= 1; m >>= 1) v += __shfl_xor(v, m, 64);
    return v;
}

// Prologue: inv_pn[k] = 1/max(||bf16(protos_k)||, eps)  (norm of ROUNDED protos,
// consistent with the bf16 values the main kernel dots against)
__global__ void proto_norm_kernel(const float* __restrict__ protos,
                                  float* __restrict__ inv_pn) {
    const int k = blockIdx.x;
    const int tid = threadIdx.x;
    const float* p = protos + k * DDIM;
    float ss = 0.0f;
#pragma unroll
    for (int i = 0; i < 2; ++i) {
        f4 a = reinterpret_cast<const f4*>(p)[tid + i * 256];
        float q;
        q = __uint_as_float((unsigned)f32_to_bf16_rne(a.x) << 16); ss += q * q;
        q = __uint_as_float((unsigned)f32_to_bf16_rne(a.y) << 16); ss += q * q;
        q = __uint_as_float((unsigned)f32_to_bf16_rne(a.z) << 16); ss += q * q;
        q = __uint_as_float((unsigned)f32_to_bf16_rne(a.w) << 16); ss += q * q;
    }
    ss = wave_reduce_add(ss);
    __shared__ float red[4];
    const int wave = tid >> 6, lane = tid & 63;
    if (lane == 0) red[wave] = ss;
    __syncthreads();
    if (tid == 0) {
        float s = red[0] + red[1] + red[2] + red[3];
        inv_pn[k] = 1.0f / fmaxf(sqrtf(s), 1e-12f);
    }
}

// Wave-per-row, bf16 protos in 32KB LDS, zero barriers in the row loop.
// amdgpu_waves_per_eu(3,4): budget 170 VGPR, squeeze target <=4 waves/EU ->
// no spill pathology (R3/R4 lesson: spills cost 2-4x, occupancy-by-spill never pays).
__global__ __launch_bounds__(BLOCK)
__attribute__((amdgpu_waves_per_eu(3, 4)))
void fused_gate_wave_kernel(const float* __restrict__ x,
                            const float* __restrict__ protos,
                            const float* __restrict__ lt,
                            const float* __restrict__ lg,
                            const float* __restrict__ lb,
                            const float* __restrict__ inv_pn,
                            float* __restrict__ out, int nrows) {
    __shared__ unsigned short plb[KP * DDIM];  // 32 KB bf16 proto bank

    const int tid = threadIdx.x;
    const int lane = tid & 63;

    // Stage protos global(fp32) -> LDS(bf16), once per block.
    {
        const f4* ps = reinterpret_cast<const f4*>(protos);
#pragma unroll
        for (int i = 0; i < (KP * DDIM / 4) / BLOCK; ++i) {
            int idx = i * BLOCK + tid;
            f4 v = ps[idx];
            ushort4 u;
            u.x = f32_to_bf16_rne(v.x); u.y = f32_to_bf16_rne(v.y);
            u.z = f32_to_bf16_rne(v.z); u.w = f32_to_bf16_rne(v.w);
            *reinterpret_cast<ushort4*>(&plb[idx * 4]) = u;
        }
    }

    const float tau = __expf(lt[0]);
    const float gamma = __expf(lg[0]);
    const float alpha = 1.0f / (1.0f + __expf(-lb[0]));
    const float inv_tau = 1.0f / tau;
    const float logK_div_tau = logf(8.0f) * inv_tau;

    float ipn[KP];
#pragma unroll
    for (int k = 0; k < KP; ++k) ipn[k] = inv_pn[k];

    __syncthreads();  // the only barrier

    const int gwave = blockIdx.x * WPB + (tid >> 6);
    const int nwaves = gridDim.x * WPB;

    for (int row = gwave; row < nrows; row += nwaves) {
        const f4* xr = reinterpret_cast<const f4*>(x + (size_t)row * DDIM);

        f4 g[8];
        float ss = 0.0f;
        float acc[KP];
#pragma unroll
        for (int k = 0; k < KP; ++k) acc[k] = 0.0f;

#pragma unroll
        for (int c = 0; c < 8; ++c) {
            f4 v = xr[c * 64 + lane];
            f4 gg;
            gg.x = gelu_f(v.x); gg.y = gelu_f(v.y);
            gg.z = gelu_f(v.z); gg.w = gelu_f(v.w);
            g[c] = gg;
            ss += gg.x * gg.x + gg.y * gg.y + gg.z * gg.z + gg.w * gg.w;

            const int ebase = c * 256 + lane * 4;
#pragma unroll
            for (int k = 0; k < KP; ++k) {
                uint2 pu = *reinterpret_cast<const uint2*>(&plb[k * DDIM + ebase]);
                float p0 = __uint_as_float(pu.x << 16);
                float p1 = __uint_as_float(pu.x & 0xFFFF0000u);
                float p2 = __uint_as_float(pu.y << 16);
                float p3 = __uint_as_float(pu.y & 0xFFFF0000u);
                acc[k] = fmaf(p0, gg.x,
                         fmaf(p1, gg.y,
                         fmaf(p2, gg.z,
                         fmaf(p3, gg.w, acc[k]))));
            }
        }

        // butterfly: sums land in ALL lanes, no broadcast/barrier needed
        ss = wave_reduce_add(ss);
#pragma unroll
        for (int k = 0; k < KP; ++k) acc[k] = wave_reduce_add(acc[k]);

        const float invn = 1.0f / fmaxf(sqrtf(ss), 1e-12f);
        float m = -1e30f;
        float z[KP];
#pragma unroll
        for (int k = 0; k < KP; ++k) {
            z[k] = acc[k] * invn * ipn[k] * tau;
            m = fmaxf(m, z[k]);
        }
        float e = 0.0f;
#pragma unroll
        for (int k = 0; k < KP; ++k) e += __expf(z[k] - m);
        float lse = m + __logf(e);
        float sms = lse * inv_tau - logK_div_tau;
        float nov = __expf(-gamma * sms);
        const float gate = 1.0f - alpha + alpha * nov;

        f4* orow = reinterpret_cast<f4*>(out + (size_t)row * DDIM);
#pragma unroll
        for (int c = 0; c < 8; ++c) {
            f4 o;
            o.x = g[c].x * gate; o.y = g[c].y * gate;
            o.z = g[c].z * gate; o.w = g[c].w * gate;
            __builtin_nontemporal_store(o, &orow[c * 64 + lane]);
        }
    }
}

extern "C" void kernel_launch(void* const* d_in, const int* in_sizes, int n_in,
                              void* d_out, int out_size, void* d_ws, size_t ws_size,
                              hipStream_t stream) {
    const float* x = (const float*)d_in[0];
    const float* protos = (const float*)d_in[1];
    const float* lt = (const float*)d_in[2];
    const float* lg = (const float*)d_in[3];
    const float* lb = (const float*)d_in[4];
    float* out = (float*)d_out;
    float* inv_pn = (float*)d_ws;

    const int nrows = in_sizes[0] / DDIM;

    proto_norm_kernel<<<KP, 256, 0, stream>>>(protos, inv_pn);

    // 1024 blocks: 4 rows per wave, 3-4 blocks resident/CU (32KB LDS each)
    fused_gate_wave_kernel<<<1024, BLOCK, 0, stream>>>(x, protos, lt, lg, lb,
                                                       inv_pn, out, nrows);
}

// Round 7
// 97.224 us; speedup vs baseline: 3.9150x; 3.9150x over previous
//
#include <hip/hip_runtime.h>
#include <math.h>

#define DDIM 2048
#define KP 8
#define BLOCK 256
#define WPB (BLOCK / 64)

typedef float f4 __attribute__((ext_vector_type(4)));

__device__ __forceinline__ unsigned short f32_to_bf16_rne(float f) {
    unsigned u = __float_as_uint(f);
    unsigned r = u + 0x7FFFu + ((u >> 16) & 1u);
    return (unsigned short)(r >> 16);
}

__device__ __forceinline__ float gelu_f(float x) {
    // 0.5*x*(1+tanh(y)) == x * sigmoid(2y),  y = 0.79788456*(x+0.044715x^3)
    float x2 = x * x;
    float inner = x * fmaf(0.044715f, x2, 1.0f);
    float e = __expf(-1.5957691216057308f * inner);   // exp(-2y)
    return x * __builtin_amdgcn_rcpf(1.0f + e);
}

__device__ __forceinline__ float wave_reduce_add(float v) {
#pragma unroll
    for (int m = 32; m >= 1; m >>= 1) v += __shfl_xor(v, m, 64);
    return v;
}

// Prologue: inv_pn[k] = 1/max(||bf16(protos_k)||, eps)  (norm of ROUNDED protos,
// consistent with the bf16 values the main kernel dots against)
__global__ void proto_norm_kernel(const float* __restrict__ protos,
                                  float* __restrict__ inv_pn) {
    const int k = blockIdx.x;
    const int tid = threadIdx.x;
    const float* p = protos + k * DDIM;
    float ss = 0.0f;
#pragma unroll
    for (int i = 0; i < 2; ++i) {
        f4 a = reinterpret_cast<const f4*>(p)[tid + i * 256];
        float q;
        q = __uint_as_float((unsigned)f32_to_bf16_rne(a.x) << 16); ss += q * q;
        q = __uint_as_float((unsigned)f32_to_bf16_rne(a.y) << 16); ss += q * q;
        q = __uint_as_float((unsigned)f32_to_bf16_rne(a.z) << 16); ss += q * q;
        q = __uint_as_float((unsigned)f32_to_bf16_rne(a.w) << 16); ss += q * q;
    }
    ss = wave_reduce_add(ss);
    __shared__ float red[4];
    const int wave = tid >> 6, lane = tid & 63;
    if (lane == 0) red[wave] = ss;
    __syncthreads();
    if (tid == 0) {
        float s = red[0] + red[1] + red[2] + red[3];
        inv_pn[k] = 1.0f / fmaxf(sqrtf(s), 1e-12f);
    }
}

// Wave-per-row, bf16 protos in 32KB LDS, zero barriers in the row loop.
// NO register-allocator constraint: every occupancy attr tried (R3/R4/R5)
// bought occupancy with spills (+95..+390 MB scratch traffic, 2-4x slower).
// R1 proved this structure allocates ~176 VGPR spill-free when unconstrained.
__global__ __launch_bounds__(BLOCK)
void fused_gate_wave_kernel(const float* __restrict__ x,
                            const float* __restrict__ protos,
                            const float* __restrict__ lt,
                            const float* __restrict__ lg,
                            const float* __restrict__ lb,
                            const float* __restrict__ inv_pn,
                            float* __restrict__ out, int nrows) {
    __shared__ unsigned short plb[KP * DDIM];  // 32 KB bf16 proto bank

    const int tid = threadIdx.x;
    const int lane = tid & 63;

    // Stage protos global(fp32) -> LDS(bf16), once per block.
    {
        const f4* ps = reinterpret_cast<const f4*>(protos);
#pragma unroll
        for (int i = 0; i < (KP * DDIM / 4) / BLOCK; ++i) {
            int idx = i * BLOCK + tid;
            f4 v = ps[idx];
            ushort4 u;
            u.x = f32_to_bf16_rne(v.x); u.y = f32_to_bf16_rne(v.y);
            u.z = f32_to_bf16_rne(v.z); u.w = f32_to_bf16_rne(v.w);
            *reinterpret_cast<ushort4*>(&plb[idx * 4]) = u;
        }
    }

    const float tau = __expf(lt[0]);
    const float gamma = __expf(lg[0]);
    const float alpha = 1.0f / (1.0f + __expf(-lb[0]));
    const float inv_tau = 1.0f / tau;
    const float logK_div_tau = logf(8.0f) * inv_tau;

    float ipn[KP];
#pragma unroll
    for (int k = 0; k < KP; ++k) ipn[k] = inv_pn[k];

    __syncthreads();  // the only barrier

    const int gwave = blockIdx.x * WPB + (tid >> 6);
    const int nwaves = gridDim.x * WPB;

    for (int row = gwave; row < nrows; row += nwaves) {
        const f4* xr = reinterpret_cast<const f4*>(x + (size_t)row * DDIM);

        f4 g[8];
        float ss = 0.0f;
        float acc[KP];
#pragma unroll
        for (int k = 0; k < KP; ++k) acc[k] = 0.0f;

#pragma unroll
        for (int c = 0; c < 8; ++c) {
            f4 v = xr[c * 64 + lane];
            f4 gg;
            gg.x = gelu_f(v.x); gg.y = gelu_f(v.y);
            gg.z = gelu_f(v.z); gg.w = gelu_f(v.w);
            g[c] = gg;
            ss += gg.x * gg.x + gg.y * gg.y + gg.z * gg.z + gg.w * gg.w;

            const int ebase = c * 256 + lane * 4;
#pragma unroll
            for (int k = 0; k < KP; ++k) {
                uint2 pu = *reinterpret_cast<const uint2*>(&plb[k * DDIM + ebase]);
                float p0 = __uint_as_float(pu.x << 16);
                float p1 = __uint_as_float(pu.x & 0xFFFF0000u);
                float p2 = __uint_as_float(pu.y << 16);
                float p3 = __uint_as_float(pu.y & 0xFFFF0000u);
                acc[k] = fmaf(p0, gg.x,
                         fmaf(p1, gg.y,
                         fmaf(p2, gg.z,
                         fmaf(p3, gg.w, acc[k]))));
            }
        }

        // butterfly: sums land in ALL lanes, no broadcast/barrier needed
        ss = wave_reduce_add(ss);
#pragma unroll
        for (int k = 0; k < KP; ++k) acc[k] = wave_reduce_add(acc[k]);

        const float invn = 1.0f / fmaxf(sqrtf(ss), 1e-12f);
        float m = -1e30f;
        float z[KP];
#pragma unroll
        for (int k = 0; k < KP; ++k) {
            z[k] = acc[k] * invn * ipn[k] * tau;
            m = fmaxf(m, z[k]);
        }
        float e = 0.0f;
#pragma unroll
        for (int k = 0; k < KP; ++k) e += __expf(z[k] - m);
        float lse = m + __logf(e);
        float sms = lse * inv_tau - logK_div_tau;
        float nov = __expf(-gamma * sms);
        const float gate = 1.0f - alpha + alpha * nov;

        f4* orow = reinterpret_cast<f4*>(out + (size_t)row * DDIM);
#pragma unroll
        for (int c = 0; c < 8; ++c) {
            f4 o;
            o.x = g[c].x * gate; o.y = g[c].y * gate;
            o.z = g[c].z * gate; o.w = g[c].w * gate;
            __builtin_nontemporal_store(o, &orow[c * 64 + lane]);
        }
    }
}

extern "C" void kernel_launch(void* const* d_in, const int* in_sizes, int n_in,
                              void* d_out, int out_size, void* d_ws, size_t ws_size,
                              hipStream_t stream) {
    const float* x = (const float*)d_in[0];
    const float* protos = (const float*)d_in[1];
    const float* lt = (const float*)d_in[2];
    const float* lg = (const float*)d_in[3];
    const float* lb = (const float*)d_in[4];
    float* out = (float*)d_out;
    float* inv_pn = (float*)d_ws;

    const int nrows = in_sizes[0] / DDIM;

    proto_norm_kernel<<<KP, 256, 0, stream>>>(protos, inv_pn);

    // 1024 blocks: 16 rows/block amortize the proto staging; ~2 blocks/CU resident
    fused_gate_wave_kernel<<<1024, BLOCK, 0, stream>>>(x, protos, lt, lg, lb,
                                                       inv_pn, out, nrows);
}